// Round 12
// baseline (120.734 us; speedup 1.0000x reference)
//
#include <hip/hip_runtime.h>

#define NDAT 16384
#define TLEN 16385
#define CPR 4                // chunks per row
#define CHUNK (NDAT / CPR)   // 4096
#define TPB 256
#define VPT (CHUNK / TPB)    // 16
#define NW (TPB / 64)        // 4 waves

__device__ __forceinline__ double wave_sum_f64(double v) {
#pragma unroll
  for (int d = 32; d >= 1; d >>= 1) v += __shfl_down(v, d, 64);
  return v;  // total in lane 0
}

// ---------------- K1: per-chunk trapezoid totals (+ zero r2) ----------------
__global__ __launch_bounds__(TPB) void k_tot(const float* __restrict__ x,
                                             double* __restrict__ wsTot,
                                             float* __restrict__ out_r2,
                                             int B) {
  const int blk = blockIdx.x;
  const int row = blk / CPR, c = blk % CPR;
  const int tid = threadIdx.x, lane = tid & 63, wid = tid >> 6;
  const float* __restrict__ xr = x + (size_t)row * TLEN + c * CHUNK;
  const int base = tid * VPT;

  float xs[VPT + 1];
#pragma unroll
  for (int j = 0; j <= VPT; ++j) xs[j] = xr[base + j];  // max idx 16384 OK
  float acc = 0.f;
#pragma unroll
  for (int j = 0; j < VPT; ++j) acc += 0.5f * (xs[j] + xs[j + 1]);

  __shared__ double swav[NW];
  const double t = wave_sum_f64((double)acc);
  if (lane == 0) swav[wid] = t;
  if (blk == 0) {  // zero r2 accumulators (d_out poisoned each replay)
    for (int i = tid; i < B; i += TPB) out_r2[i] = 0.f;
  }
  __syncthreads();
  if (tid == 0) {
    double s = 0.0;
#pragma unroll
    for (int w = 0; w < NW; ++w) s += swav[w];
    wsTot[blk] = s;
  }
}

// ---------------- K2: Gram/rhs partial sums per chunk -----------------------
__global__ __launch_bounds__(TPB) void k_gram(const float* __restrict__ x,
                                              const float* __restrict__ params,
                                              const double* __restrict__ wsTot,
                                              double* __restrict__ wsGram) {
  const int blk = blockIdx.x;
  const int row = blk / CPR, c = blk % CPR;
  const int tid = threadIdx.x, lane = tid & 63, wid = tid >> 6;
  const float r = params[0], ny = params[1];
  const bool rhalf = (r == 0.5f);
  const float* __restrict__ xr = x + (size_t)row * TLEN + c * CHUNK;
  const int base = tid * VPT;

  float xs[VPT + 1];
#pragma unroll
  for (int j = 0; j <= VPT; ++j) xs[j] = xr[base + j];
  float tf = 0.f;
#pragma unroll
  for (int j = 0; j < VPT; ++j) tf += 0.5f * (xs[j] + xs[j + 1]);

  // wave inclusive scan of per-thread totals (fp64)
  double t = (double)tf;
#pragma unroll
  for (int d = 1; d < 64; d <<= 1) {
    double o = __shfl_up(t, d, 64);
    if (lane >= d) t += o;
  }
  __shared__ double swav[NW];
  if (lane == 63) swav[wid] = t;
  __syncthreads();

  double cOff = (double)ny;
#pragma unroll
  for (int cc = 0; cc < CPR; ++cc)
    if (cc < c) cOff += wsTot[row * CPR + cc];
  double cross = 0.0;
#pragma unroll
  for (int w = 0; w < NW; ++w)
    if (w < wid) cross += swav[w];
  const float offf = (float)(cOff + cross + (t - (double)tf));

  float s_u = 0.f, s_u2 = 0.f, s_u15 = 0.f, s_xu = 0.f, s_xv = 0.f;
  if (rhalf) {
    float acc = 0.f;
#pragma unroll
    for (int j = 0; j < VPT; ++j) {
      acc += 0.5f * (xs[j] + xs[j + 1]);  // identical chain order everywhere
      const float uu = offf + acc;
      const float vh = sqrtf(uu);
      const float xd = xs[j + 1];
      s_u += uu;
      s_u2 = fmaf(uu, uu, s_u2);
      s_u15 = fmaf(uu, vh, s_u15);
      s_xu = fmaf(xd, uu, s_xu);
      s_xv = fmaf(xd, vh, s_xv);
    }
  } else {
    float acc = 0.f;
#pragma unroll
    for (int j = 0; j < VPT; ++j) {
      acc += 0.5f * (xs[j] + xs[j + 1]);
      const float uu = offf + acc;
      const float vh = powf(uu, r);
      const float xd = xs[j + 1];
      s_u += uu;
      s_u2 = fmaf(uu, uu, s_u2);
      s_u15 = fmaf(uu, vh, s_u15);
      s_xu = fmaf(xd, uu, s_xu);
      s_xv = fmaf(xd, vh, s_xv);
    }
  }

  __shared__ double sred[NW][5];
  double vals[5] = {(double)s_u, (double)s_u2, (double)s_u15, (double)s_xu,
                    (double)s_xv};
#pragma unroll
  for (int i = 0; i < 5; ++i) vals[i] = wave_sum_f64(vals[i]);
  if (lane == 0) {
#pragma unroll
    for (int i = 0; i < 5; ++i) sred[wid][i] = vals[i];
  }
  __syncthreads();
  if (tid == 0) {
#pragma unroll
    for (int i = 0; i < 5; ++i) {
      double s = 0.0;
#pragma unroll
      for (int w = 0; w < NW; ++w) s += sred[w][i];
      wsGram[(size_t)blk * 5 + i] = s;
    }
  }
}

// ---------------- K3: solve + outputs ---------------------------------------
__global__ __launch_bounds__(TPB) void k_out(
    const float* __restrict__ x, const float* __restrict__ params,
    const double* __restrict__ wsTot, const double* __restrict__ wsGram,
    float* __restrict__ out_coeffs, float* __restrict__ out_xhat,
    float* __restrict__ out_res, float* __restrict__ out_r2) {
  const int blk = blockIdx.x;
  const int row = blk / CPR, c = blk % CPR;
  const int tid = threadIdx.x, lane = tid & 63, wid = tid >> 6;
  const float r = params[0], ny = params[1];
  const bool rhalf = (r == 0.5f);
  const float* __restrict__ xr = x + (size_t)row * TLEN + c * CHUNK;
  const int base = tid * VPT;

  float xs[VPT + 1];
#pragma unroll
  for (int j = 0; j <= VPT; ++j) xs[j] = xr[base + j];
  float tf = 0.f;
#pragma unroll
  for (int j = 0; j < VPT; ++j) tf += 0.5f * (xs[j] + xs[j + 1]);

  double t = (double)tf;
#pragma unroll
  for (int d = 1; d < 64; d <<= 1) {
    double o = __shfl_up(t, d, 64);
    if (lane >= d) t += o;
  }
  __shared__ double swav[NW];
  __shared__ float cbc[2];
  if (lane == 63) swav[wid] = t;
  __syncthreads();

  double cOff = (double)ny;
#pragma unroll
  for (int cc = 0; cc < CPR; ++cc)
    if (cc < c) cOff += wsTot[row * CPR + cc];
  double cross = 0.0;
#pragma unroll
  for (int w = 0; w < NW; ++w)
    if (w < wid) cross += swav[w];
  const float offf = (float)(cOff + cross + (t - (double)tf));

  if (tid == 0) {
    double g[5] = {0.0, 0.0, 0.0, 0.0, 0.0};
    for (int cc = 0; cc < CPR; ++cc) {
#pragma unroll
      for (int i = 0; i < 5; ++i)
        g[i] += wsGram[((size_t)row * CPR + cc) * 5 + i];
    }
    const double g11 = g[0];  // sum u
    const double g00 = g[1];  // sum u^2
    const double g01 = g[2];  // sum u^{1+r}
    const double b0 = g[3];   // sum xd*u
    const double b1 = g[4];   // sum xd*u^r

    // Replicate jnp.linalg.pinv: fp32 SVD, rcond = 10*16384*eps = 0.01953125
    const double tr = g00 + g11;
    const double det = g00 * g11 - g01 * g01;
    const double disc = sqrt(fmax(tr * tr - 4.0 * det, 0.0));
    const double l1 = 0.5 * (tr + disc);
    const double l2 = (l1 > 0.0) ? fmax(det / l1, 0.0) : 0.0;
    const double s1 = sqrt(fmax(l1, 0.0));
    const double s2 = sqrt(l2);
    const double rcond = 0.01953125;

    double c0, c1;
    if (s2 > rcond * s1) {
      c0 = (g11 * b0 - g01 * b1) / det;  // rank-2 normal equations
      c1 = (g00 * b1 - g01 * b0) / det;
    } else if (s1 > 0.0) {
      // rank-1 truncated pinv: coeffs = ((b.e1)/l1)*e1, e1 ~ [l1-g11, g01]
      double w0 = l1 - g11, w1 = g01;
      double nrm = sqrt(w0 * w0 + w1 * w1);
      double e0 = 1.0, e1 = 0.0;
      if (nrm > 0.0) {
        e0 = w0 / nrm;
        e1 = w1 / nrm;
      }
      const double gam = (b0 * e0 + b1 * e1) / l1;
      c0 = gam * e0;
      c1 = gam * e1;
    } else {
      c0 = 0.0;
      c1 = 0.0;
    }
    cbc[0] = (float)c0;
    cbc[1] = (float)c1;
    if (c == 0) {
      out_coeffs[2 * row] = (float)c0;
      out_coeffs[2 * row + 1] = (float)c1;
    }
  }
  __syncthreads();
  const float c0 = cbc[0];
  const float c1 = cbc[1];

  float* __restrict__ oxh = out_xhat + (size_t)row * NDAT + c * CHUNK + base;
  float* __restrict__ ors = out_res + (size_t)row * NDAT + c * CHUNK + base;

  float r2f = 0.f;
  if (rhalf) {
    float acc = 0.f;
#pragma unroll
    for (int q = 0; q < VPT / 4; ++q) {
      float xh[4], rs[4];
#pragma unroll
      for (int i = 0; i < 4; ++i) {
        const int j = q * 4 + i;
        acc += 0.5f * (xs[j] + xs[j + 1]);  // same chain as K2
        const float uu = offf + acc;
        const float vh = sqrtf(uu);
        xh[i] = fmaf(c0, uu, c1 * vh);
        rs[i] = xs[j + 1] - xh[i];
        r2f = fmaf(rs[i], rs[i], r2f);
      }
      *reinterpret_cast<float4*>(oxh + 4 * q) =
          make_float4(xh[0], xh[1], xh[2], xh[3]);
      *reinterpret_cast<float4*>(ors + 4 * q) =
          make_float4(rs[0], rs[1], rs[2], rs[3]);
    }
  } else {
    float acc = 0.f;
#pragma unroll
    for (int q = 0; q < VPT / 4; ++q) {
      float xh[4], rs[4];
#pragma unroll
      for (int i = 0; i < 4; ++i) {
        const int j = q * 4 + i;
        acc += 0.5f * (xs[j] + xs[j + 1]);
        const float uu = offf + acc;
        const float vh = powf(uu, r);
        xh[i] = fmaf(c0, uu, c1 * vh);
        rs[i] = xs[j + 1] - xh[i];
        r2f = fmaf(rs[i], rs[i], r2f);
      }
      *reinterpret_cast<float4*>(oxh + 4 * q) =
          make_float4(xh[0], xh[1], xh[2], xh[3]);
      *reinterpret_cast<float4*>(ors + 4 * q) =
          make_float4(rs[0], rs[1], rs[2], rs[3]);
    }
  }

  __shared__ double sr2[NW];
  const double r2 = wave_sum_f64((double)r2f);
  if (lane == 0) sr2[wid] = r2;
  __syncthreads();
  if (tid == 0) {
    double s = 0.0;
#pragma unroll
    for (int w = 0; w < NW; ++w) s += sr2[w];
    atomicAdd(out_r2 + row, (float)s);
  }
}

extern "C" void kernel_launch(void* const* d_in, const int* in_sizes, int n_in,
                              void* d_out, int out_size, void* d_ws,
                              size_t ws_size, hipStream_t stream) {
  const float* x = (const float*)d_in[0];
  const float* params = (const float*)d_in[1];
  float* out = (float*)d_out;
  const int B = in_sizes[0] / TLEN;  // 512
  const int nblk = B * CPR;          // 2048

  float* out_coeffs = out;
  float* out_xhat = out + (size_t)2 * B;
  float* out_res = out + (size_t)2 * B + (size_t)B * NDAT;
  float* out_r2 = out + (size_t)2 * B + (size_t)2 * B * NDAT;

  double* wsTot = (double*)d_ws;                    // nblk doubles (16 KB)
  double* wsGram = (double*)d_ws + nblk;            // nblk*5 doubles (80 KB)

  k_tot<<<dim3(nblk), dim3(TPB), 0, stream>>>(x, wsTot, out_r2, B);
  k_gram<<<dim3(nblk), dim3(TPB), 0, stream>>>(x, params, wsTot, wsGram);
  k_out<<<dim3(nblk), dim3(TPB), 0, stream>>>(x, params, wsTot, wsGram,
                                              out_coeffs, out_xhat, out_res,
                                              out_r2);
}